// Round 17
// baseline (213.050 us; speedup 1.0000x reference)
//
#include <hip/hip_runtime.h>
#include <hip/hip_bf16.h>

#define NN 100000   // nodes
#define NE 50000    // edges
#define NZ 800000   // incidences
#define D  128
#define NSEG (NE + NN)   // 150000
#define FILL_B 782       // blocks per fill pass = ceil(NZ/4/256)
#define G_GEMM 782       // (NN+127)/128
#define G_HIST 391       // ceil(NZ/8/256)
#define G_EDGE 12500     // NE*64/256
#define G_FILLN (2 * FILL_B)

typedef __bf16 bf16x8 __attribute__((ext_vector_type(8)));
typedef float f32x4 __attribute__((ext_vector_type(4)));

static __device__ __forceinline__ unsigned short f2bf(float f) {
  union { float f; unsigned u; } v; v.f = f;
  unsigned r = (v.u + 0x7FFFu + ((v.u >> 16) & 1u)) >> 16;  // RNE
  return (unsigned short)r;
}
static __device__ __forceinline__ float bf2f(unsigned short h) {
  union { unsigned u; float f; } v; v.u = ((unsigned)h) << 16;
  return v.f;
}

// ---------------- fused: hist_rank (blocks [0,G_HIST)) + GEMM (rest) ----------------
// hist-first: atomic pipe saturated from t=0 (R15: -8us). GEMM is LDS-FREE (no
// kernel-wide LDS reservation -> hist blocks pack densely) and reads x0 with
// NON-TEMPORAL loads (x0 is read-exactly-once streaming; keep L2 for the atomic
// path). W fragment reads stay cached (16KB/k-slice, L1-hot). Swapped operands
// (A=W channels, B=x0 rows) -> acc regs = 4 consecutive channels of one node row
// -> one 8B ushort4 store.
__global__ __launch_bounds__(256) void unisage_gemm_hist(const float* __restrict__ x0,
                                                         const float* __restrict__ W,
                                                         const float* __restrict__ bias,
                                                         unsigned short* __restrict__ xb,
                                                         const int* __restrict__ nid,
                                                         const int* __restrict__ eid,
                                                         int* __restrict__ cnt,
                                                         unsigned short* __restrict__ rank_e,
                                                         unsigned short* __restrict__ rank_n) {
  if (blockIdx.x < G_HIST) {
    // ---- hist_rank: 8 items/thread, u16 ranks ----
    int base = (blockIdx.x * 256 + threadIdx.x) * 8;
    if (base >= NZ) return;
    int4 ea = *(const int4*)(eid + base);
    int4 eb = *(const int4*)(eid + base + 4);
    int4 na = *(const int4*)(nid + base);
    int4 nb = *(const int4*)(nid + base + 4);
    int e[8] = {ea.x, ea.y, ea.z, ea.w, eb.x, eb.y, eb.z, eb.w};
    int v[8] = {na.x, na.y, na.z, na.w, nb.x, nb.y, nb.z, nb.w};
    unsigned short re[8], rn[8];
#pragma unroll
    for (int j = 0; j < 8; ++j) re[j] = (unsigned short)atomicAdd(&cnt[e[j]], 1);
#pragma unroll
    for (int j = 0; j < 8; ++j) rn[j] = (unsigned short)atomicAdd(&cnt[NE + v[j]], 1);
    ushort4 r0 = {re[0], re[1], re[2], re[3]};
    ushort4 r1 = {re[4], re[5], re[6], re[7]};
    ushort4 s0 = {rn[0], rn[1], rn[2], rn[3]};
    ushort4 s1 = {rn[4], rn[5], rn[6], rn[7]};
    *(ushort4*)(rank_e + base) = r0;
    *(ushort4*)(rank_e + base + 4) = r1;
    *(ushort4*)(rank_n + base) = s0;
    *(ushort4*)(rank_n + base + 4) = s1;
  } else {
    const int t = threadIdx.x;
    const int wave = t >> 6;
    const int lane = t & 63;
    const int lr = lane & 15;   // A row (channel) / B col (node row)
    const int lg = lane >> 4;   // k-group / C channel-subgroup
    const int rowbase = (blockIdx.x - G_HIST) * 128 + wave * 32;

    f32x4 acc[2][8] = {};  // [node-row-group rf][channel-frag cf]

#pragma unroll
    for (int ks = 0; ks < 4; ++ks) {
      const int k0 = ks * 32 + lg * 8;
      bf16x8 xf[2];
#pragma unroll
      for (int rf = 0; rf < 2; ++rf) {
        int row = rowbase + rf * 16 + lr;
        row = row < NN ? row : NN - 1;  // clamp; stores are guarded
        const float* src = x0 + (size_t)row * D + k0;
        f32x4 f0 = __builtin_nontemporal_load((const f32x4*)src);
        f32x4 f1 = __builtin_nontemporal_load((const f32x4*)(src + 4));
        xf[rf][0] = (__bf16)f0[0]; xf[rf][1] = (__bf16)f0[1];
        xf[rf][2] = (__bf16)f0[2]; xf[rf][3] = (__bf16)f0[3];
        xf[rf][4] = (__bf16)f1[0]; xf[rf][5] = (__bf16)f1[1];
        xf[rf][6] = (__bf16)f1[2]; xf[rf][7] = (__bf16)f1[3];
      }
#pragma unroll
      for (int cf = 0; cf < 8; ++cf) {
        const float* wsrc = W + (size_t)(cf * 16 + lr) * D + k0;
        float4 w0 = *(const float4*)(wsrc);
        float4 w1 = *(const float4*)(wsrc + 4);
        bf16x8 wf;
        wf[0] = (__bf16)w0.x; wf[1] = (__bf16)w0.y;
        wf[2] = (__bf16)w0.z; wf[3] = (__bf16)w0.w;
        wf[4] = (__bf16)w1.x; wf[5] = (__bf16)w1.y;
        wf[6] = (__bf16)w1.z; wf[7] = (__bf16)w1.w;
        acc[0][cf] = __builtin_amdgcn_mfma_f32_16x16x32_bf16(wf, xf[0], acc[0][cf], 0, 0, 0);
        acc[1][cf] = __builtin_amdgcn_mfma_f32_16x16x32_bf16(wf, xf[1], acc[1][cf], 0, 0, 0);
      }
    }

#pragma unroll
    for (int cf = 0; cf < 8; ++cf) {
      float4 bv = *(const float4*)(bias + cf * 16 + lg * 4);  // channels cf*16+lg*4..+3
#pragma unroll
      for (int rf = 0; rf < 2; ++rf) {
        int row = rowbase + rf * 16 + lr;
        if (row < NN) {
          ushort4 o;
          o.x = f2bf(acc[rf][cf][0] + bv.x);
          o.y = f2bf(acc[rf][cf][1] + bv.y);
          o.z = f2bf(acc[rf][cf][2] + bv.z);
          o.w = f2bf(acc[rf][cf][3] + bv.w);
          *(ushort4*)(xb + (size_t)row * D + cf * 16 + lg * 4) = o;
        }
      }
    }
  }
}

// ---------------- scans ----------------
__global__ void unisage_scan_k1(const int* __restrict__ in, int* __restrict__ bsum, int n) {
  __shared__ int sh[256];
  int t = threadIdx.x;
  int base = blockIdx.x * 1024 + t * 4;
  int s = 0;
#pragma unroll
  for (int j = 0; j < 4; ++j)
    if (base + j < n) s += in[base + j];
  sh[t] = s;
  __syncthreads();
  for (int o = 128; o > 0; o >>= 1) {
    if (t < o) sh[t] += sh[t + o];
    __syncthreads();
  }
  if (t == 0) bsum[blockIdx.x] = sh[0];
}

// k3 with the block-sum scan folded in: every block locally scans bsum[0..nb)
__global__ void unisage_scan_k3(const int* __restrict__ in, const int* __restrict__ bsum,
                                int* __restrict__ out, int n, int nb) {
  __shared__ int sh[256];
  int t = threadIdx.x;
  int bv = (t < nb) ? bsum[t] : 0;
  sh[t] = bv;
  __syncthreads();
  for (int o = 1; o < 256; o <<= 1) {
    int add = (t >= o) ? sh[t - o] : 0;
    __syncthreads();
    sh[t] += add;
    __syncthreads();
  }
  int bbase = (blockIdx.x == 0) ? 0 : sh[blockIdx.x - 1];
  __syncthreads();

  int base = blockIdx.x * 1024 + t * 4;
  int v[4];
#pragma unroll
  for (int j = 0; j < 4; ++j) v[j] = (base + j < n) ? in[base + j] : 0;
  int tsum = v[0] + v[1] + v[2] + v[3];
  sh[t] = tsum;
  __syncthreads();
  for (int o = 1; o < 256; o <<= 1) {
    int add = (t >= o) ? sh[t - o] : 0;
    __syncthreads();
    sh[t] += add;
    __syncthreads();
  }
  int run = sh[t] - tsum + bbase;
#pragma unroll
  for (int j = 0; j < 4; ++j) {
    if (base + j < n) out[base + j] = run;
    run += v[j];
  }
}

// ---------------- fill_e: edge side only, 2 passes over [0,NE) ----------------
__global__ void unisage_fill_e(const int* __restrict__ nid, const int* __restrict__ eid,
                               const unsigned short* __restrict__ rank_e,
                               const int* __restrict__ off,
                               int* __restrict__ csr_e) {
  const int R = NE / 2;  // 25000
  int pass = blockIdx.x / FILL_B;
  int base = ((blockIdx.x % FILL_B) * 256 + threadIdx.x) * 4;
  if (base >= NZ) return;
  int lo = pass * R, hi = lo + R;
  int4 e4 = *(const int4*)(eid + base);
  int4 n4 = *(const int4*)(nid + base);
  ushort4 re4 = *(const ushort4*)(rank_e + base);
  int e[4] = {e4.x, e4.y, e4.z, e4.w};
  int v[4] = {n4.x, n4.y, n4.z, n4.w};
  unsigned short re[4] = {re4.x, re4.y, re4.z, re4.w};
#pragma unroll
  for (int j = 0; j < 4; ++j) {
    if (e[j] >= lo && e[j] < hi) csr_e[off[e[j]] + (int)re[j]] = v[j];
  }
}

// ---------------- fused: fill_n (blocks [0,G_FILLN)) + edge_agg (rest) ----------------
#define QRED(x) { x += __shfl_xor(x, 16, 64); x += __shfl_xor(x, 32, 64); }

__global__ void unisage_edge_fill(const unsigned short* __restrict__ xb,
                                  const int* __restrict__ csr_e,
                                  const int* __restrict__ off, const int* __restrict__ cnt,
                                  unsigned short* __restrict__ m01b,
                                  const int* __restrict__ nid, const int* __restrict__ eid,
                                  const unsigned short* __restrict__ rank_n,
                                  int* __restrict__ csr_n) {
  if (blockIdx.x < G_FILLN) {
    // ---- fill_n: node side, 2 passes over [NE, NE+NN) ----
    const int R = NN / 2;  // 50000
    int pass = blockIdx.x / FILL_B;
    int base = ((blockIdx.x % FILL_B) * 256 + threadIdx.x) * 4;
    if (base >= NZ) return;
    int lo = NE + pass * R, hi = lo + R;
    int4 e4 = *(const int4*)(eid + base);
    int4 n4 = *(const int4*)(nid + base);
    ushort4 rn4 = *(const ushort4*)(rank_n + base);
    int e[4] = {e4.x, e4.y, e4.z, e4.w};
    int v[4] = {n4.x, n4.y, n4.z, n4.w};
    unsigned short rn[4] = {rn4.x, rn4.y, rn4.z, rn4.w};
#pragma unroll
    for (int j = 0; j < 4; ++j) {
      int s = NE + v[j];
      if (s >= lo && s < hi) csr_n[off[s] + (int)rn[j] - NZ] = e[j];
    }
  } else {
    // ---- edge_agg: 1 wave/segment, 4 rows/instr, 16B per lane ----
    int w = ((blockIdx.x - G_FILLN) * 256 + threadIdx.x) >> 6;  // edge id
    int lane = threadIdx.x & 63;
    if (w >= NE) return;
    int quad = lane >> 4;
    int sl = lane & 15;
    int beg = off[w];
    int deg = cnt[w];
    int end = beg + deg;
    float a0 = 0, a1 = 0, a2 = 0, a3 = 0, a4 = 0, a5 = 0, a6 = 0, a7 = 0;
    for (int base = beg; base < end; base += 64) {
      int m = min(64, end - base);
      int idx = (lane < m) ? csr_e[base + lane] : 0;
      int iters = (m + 3) >> 2;
      for (int jj = 0; jj < iters; ++jj) {
        int p = 4 * jj + quad;
        int r = __shfl(idx, p, 64);
        if (p < m) {
          uint4 vv = *(const uint4*)(xb + (size_t)r * D + sl * 8);
          a0 += bf2f((unsigned short)(vv.x & 0xffffu)); a1 += bf2f((unsigned short)(vv.x >> 16));
          a2 += bf2f((unsigned short)(vv.y & 0xffffu)); a3 += bf2f((unsigned short)(vv.y >> 16));
          a4 += bf2f((unsigned short)(vv.z & 0xffffu)); a5 += bf2f((unsigned short)(vv.z >> 16));
          a6 += bf2f((unsigned short)(vv.w & 0xffffu)); a7 += bf2f((unsigned short)(vv.w >> 16));
        }
      }
    }
    QRED(a0) QRED(a1) QRED(a2) QRED(a3) QRED(a4) QRED(a5) QRED(a6) QRED(a7)
    if (quad == 0) {
      uint4 o;
      o.x = (unsigned)f2bf(a0) | ((unsigned)f2bf(a1) << 16);
      o.y = (unsigned)f2bf(a2) | ((unsigned)f2bf(a3) << 16);
      o.z = (unsigned)f2bf(a4) | ((unsigned)f2bf(a5) << 16);
      o.w = (unsigned)f2bf(a6) | ((unsigned)f2bf(a7) << 16);
      *(uint4*)(m01b + (size_t)w * D + sl * 8) = o;
    }
  }
}

// ---------------- node agg: 2 nodes/wave + NT out stores (R9 form, A/B-proven) --------
__global__ void unisage_node_agg(const unsigned short* __restrict__ xb,
                                 const unsigned short* __restrict__ m01b,
                                 const int* __restrict__ csr_n,
                                 const int* __restrict__ off, const int* __restrict__ cnt,
                                 float* __restrict__ out) {
  int wv = (blockIdx.x * 256 + threadIdx.x) >> 6;  // wave id
  int lane = threadIdx.x & 63;
  int half = lane >> 5;
  int sub = lane & 31;
  int rg = sub >> 4;
  int sl = sub & 15;
  int w = wv * 2 + half;  // node id
  if (w >= NN) return;
  int deg = cnt[NE + w];
  int beg = off[NE + w] - NZ;
  int end = beg + deg;
  float a0 = 0, a1 = 0, a2 = 0, a3 = 0, a4 = 0, a5 = 0, a6 = 0, a7 = 0;
  for (int base = beg; base < end; base += 32) {
    int m = min(32, end - base);
    int idx = (sub < m) ? csr_n[base + sub] : 0;
    int iters = (m + 1) >> 1;
    for (int jj = 0; jj < iters; ++jj) {
      int p = 2 * jj + rg;
      int r = __shfl(idx, half * 32 + p, 64);
      if (p < m) {
        uint4 vv = *(const uint4*)(m01b + (size_t)r * D + sl * 8);
        a0 += bf2f((unsigned short)(vv.x & 0xffffu)); a1 += bf2f((unsigned short)(vv.x >> 16));
        a2 += bf2f((unsigned short)(vv.y & 0xffffu)); a3 += bf2f((unsigned short)(vv.y >> 16));
        a4 += bf2f((unsigned short)(vv.z & 0xffffu)); a5 += bf2f((unsigned short)(vv.z >> 16));
        a6 += bf2f((unsigned short)(vv.w & 0xffffu)); a7 += bf2f((unsigned short)(vv.w >> 16));
      }
    }
  }
  a0 += __shfl_xor(a0, 16, 64); a1 += __shfl_xor(a1, 16, 64);
  a2 += __shfl_xor(a2, 16, 64); a3 += __shfl_xor(a3, 16, 64);
  a4 += __shfl_xor(a4, 16, 64); a5 += __shfl_xor(a5, 16, 64);
  a6 += __shfl_xor(a6, 16, 64); a7 += __shfl_xor(a7, 16, 64);
  if (rg == 0) {
    float inv = 1.0f / fmaxf((float)deg, 1.0f);
    uint4 xr = *(const uint4*)(xb + (size_t)w * D + sl * 8);
    f32x4 o0, o1;
    o0[0] = bf2f((unsigned short)(xr.x & 0xffffu)) + a0 * inv;
    o0[1] = bf2f((unsigned short)(xr.x >> 16))     + a1 * inv;
    o0[2] = bf2f((unsigned short)(xr.y & 0xffffu)) + a2 * inv;
    o0[3] = bf2f((unsigned short)(xr.y >> 16))     + a3 * inv;
    o1[0] = bf2f((unsigned short)(xr.z & 0xffffu)) + a4 * inv;
    o1[1] = bf2f((unsigned short)(xr.z >> 16))     + a5 * inv;
    o1[2] = bf2f((unsigned short)(xr.w & 0xffffu)) + a6 * inv;
    o1[3] = bf2f((unsigned short)(xr.w >> 16))     + a7 * inv;
    __builtin_nontemporal_store(o0, (f32x4*)(out + (size_t)w * D + sl * 8));
    __builtin_nontemporal_store(o1, (f32x4*)(out + (size_t)w * D + sl * 8 + 4));
  }
}

extern "C" void kernel_launch(void* const* d_in, const int* in_sizes, int n_in,
                              void* d_out, int out_size, void* d_ws, size_t ws_size,
                              hipStream_t stream) {
  const float* x0   = (const float*)d_in[0];
  const float* W    = (const float*)d_in[1];
  const float* bias = (const float*)d_in[2];
  const int* nid    = (const int*)d_in[3];
  const int* eid    = (const int*)d_in[4];
  float* out = (float*)d_out;

  unsigned short* xb   = (unsigned short*)d_ws;           // NN*D bf16 (25.6 MB)
  unsigned short* m01b = xb + (size_t)NN * D;             // NE*D bf16 (12.8 MB)
  int* cnt   = (int*)(m01b + (size_t)NE * D);             // NSEG
  int* off   = cnt + 150016;                              // NSEG
  unsigned short* rank_e = (unsigned short*)(off + 150016);  // NZ u16
  unsigned short* rank_n = rank_e + NZ;                      // NZ u16
  int* csr_e = (int*)(rank_n + NZ);                       // NZ
  int* csr_n = csr_e + NZ;                                // NZ
  int* bsum  = csr_n + NZ;                                // 256

  hipMemsetAsync(cnt, 0, NSEG * sizeof(int), stream);

  unisage_gemm_hist<<<G_HIST + G_GEMM, 256, 0, stream>>>(x0, W, bias, xb, nid, eid,
                                                         cnt, rank_e, rank_n);

  const int nb = (NSEG + 1023) / 1024;  // 147
  unisage_scan_k1<<<nb, 256, 0, stream>>>(cnt, bsum, NSEG);
  unisage_scan_k3<<<nb, 256, 0, stream>>>(cnt, bsum, off, NSEG, nb);

  unisage_fill_e<<<2 * FILL_B, 256, 0, stream>>>(nid, eid, rank_e, off, csr_e);

  unisage_edge_fill<<<G_FILLN + G_EDGE, 256, 0, stream>>>(xb, csr_e, off, cnt, m01b,
                                                          nid, eid, rank_n, csr_n);

  unisage_node_agg<<<(NN / 2 * 64) / 256, 256, 0, stream>>>(xb, m01b, csr_n, off, cnt, out);
}

// Round 18
// 188.627 us; speedup vs baseline: 1.1295x; 1.1295x over previous
//
#include <hip/hip_runtime.h>
#include <hip/hip_bf16.h>

#define NN 100000   // nodes
#define NE 50000    // edges
#define NZ 800000   // incidences
#define D  128
#define NSEG (NE + NN)   // 150000
#define FILL_B 782       // blocks per fill pass = ceil(NZ/4/256)
#define G_GEMM 782       // (NN+127)/128
#define G_HIST 391       // ceil(NZ/8/256)
#define G_EDGE 6250      // NE/2*64/256 (2 edges per wave)
#define G_FILLN (2 * FILL_B)

typedef __bf16 bf16x8 __attribute__((ext_vector_type(8)));
typedef float f32x4 __attribute__((ext_vector_type(4)));

static __device__ __forceinline__ unsigned short f2bf(float f) {
  union { float f; unsigned u; } v; v.f = f;
  unsigned r = (v.u + 0x7FFFu + ((v.u >> 16) & 1u)) >> 16;  // RNE
  return (unsigned short)r;
}
static __device__ __forceinline__ float bf2f(unsigned short h) {
  union { unsigned u; float f; } v; v.u = ((unsigned)h) << 16;
  return v.f;
}

// ---------------- fused: hist_rank (blocks [0,G_HIST)) + GEMM (rest) ----------------
// hist-first: atomic pipe saturated from t=0 (R15: -8us). GEMM: LDS-staged W
// (R17 A/B: LDS-free + NT x0 loads REGRESSED 93->110us — x0 is IC-resident, NT
// forfeits that; LDS version holds 26% occupancy). Swapped operands (A=W channels,
// B=x0 rows) -> acc regs = 4 consecutive channels of one node row -> 8B store.
__global__ __launch_bounds__(256) void unisage_gemm_hist(const float* __restrict__ x0,
                                                         const float* __restrict__ W,
                                                         const float* __restrict__ bias,
                                                         unsigned short* __restrict__ xb,
                                                         const int* __restrict__ nid,
                                                         const int* __restrict__ eid,
                                                         int* __restrict__ cnt,
                                                         unsigned short* __restrict__ rank_e,
                                                         unsigned short* __restrict__ rank_n) {
  __shared__ __bf16 Wl[128][136];
  if (blockIdx.x < G_HIST) {
    // ---- hist_rank: 8 items/thread, u16 ranks ----
    int base = (blockIdx.x * 256 + threadIdx.x) * 8;
    if (base >= NZ) return;
    int4 ea = *(const int4*)(eid + base);
    int4 eb = *(const int4*)(eid + base + 4);
    int4 na = *(const int4*)(nid + base);
    int4 nb = *(const int4*)(nid + base + 4);
    int e[8] = {ea.x, ea.y, ea.z, ea.w, eb.x, eb.y, eb.z, eb.w};
    int v[8] = {na.x, na.y, na.z, na.w, nb.x, nb.y, nb.z, nb.w};
    unsigned short re[8], rn[8];
#pragma unroll
    for (int j = 0; j < 8; ++j) re[j] = (unsigned short)atomicAdd(&cnt[e[j]], 1);
#pragma unroll
    for (int j = 0; j < 8; ++j) rn[j] = (unsigned short)atomicAdd(&cnt[NE + v[j]], 1);
    ushort4 r0 = {re[0], re[1], re[2], re[3]};
    ushort4 r1 = {re[4], re[5], re[6], re[7]};
    ushort4 s0 = {rn[0], rn[1], rn[2], rn[3]};
    ushort4 s1 = {rn[4], rn[5], rn[6], rn[7]};
    *(ushort4*)(rank_e + base) = r0;
    *(ushort4*)(rank_e + base + 4) = r1;
    *(ushort4*)(rank_n + base) = s0;
    *(ushort4*)(rank_n + base + 4) = s1;
  } else {
    const int t = threadIdx.x;
#pragma unroll
    for (int i = 0; i < 16; ++i) {
      int idx = i * 1024 + t * 4;
      int dout = idx >> 7;
      int k = idx & 127;
      float4 wv = *(const float4*)(W + idx);
      Wl[dout][k + 0] = (__bf16)wv.x;
      Wl[dout][k + 1] = (__bf16)wv.y;
      Wl[dout][k + 2] = (__bf16)wv.z;
      Wl[dout][k + 3] = (__bf16)wv.w;
    }
    __syncthreads();

    const int wave = t >> 6;
    const int lane = t & 63;
    const int lr = lane & 15;   // A row (channel) / B col (node row)
    const int lg = lane >> 4;   // k-group / C channel-subgroup
    const int rowbase = (blockIdx.x - G_HIST) * 128 + wave * 32;

    f32x4 acc[2][8] = {};  // [node-row-group rf][channel-frag cf]

#pragma unroll
    for (int ks = 0; ks < 4; ++ks) {
      const int k0 = ks * 32 + lg * 8;
      bf16x8 wf[8];
#pragma unroll
      for (int cf = 0; cf < 8; ++cf)
        wf[cf] = *(const bf16x8*)&Wl[cf * 16 + lr][k0];   // A: channel cf*16+lr
#pragma unroll
      for (int rf = 0; rf < 2; ++rf) {
        int row = rowbase + rf * 16 + lr;
        row = row < NN ? row : NN - 1;  // clamp; stores are guarded
        const float* src = x0 + (size_t)row * D + k0;
        float4 f0 = *(const float4*)(src);
        float4 f1 = *(const float4*)(src + 4);
        bf16x8 xf;
        xf[0] = (__bf16)f0.x; xf[1] = (__bf16)f0.y;
        xf[2] = (__bf16)f0.z; xf[3] = (__bf16)f0.w;
        xf[4] = (__bf16)f1.x; xf[5] = (__bf16)f1.y;
        xf[6] = (__bf16)f1.z; xf[7] = (__bf16)f1.w;
#pragma unroll
        for (int cf = 0; cf < 8; ++cf)
          acc[rf][cf] = __builtin_amdgcn_mfma_f32_16x16x32_bf16(wf[cf], xf, acc[rf][cf], 0, 0, 0);
      }
    }

#pragma unroll
    for (int cf = 0; cf < 8; ++cf) {
      float4 bv = *(const float4*)(bias + cf * 16 + lg * 4);  // channels cf*16+lg*4..+3
#pragma unroll
      for (int rf = 0; rf < 2; ++rf) {
        int row = rowbase + rf * 16 + lr;
        if (row < NN) {
          ushort4 o;
          o.x = f2bf(acc[rf][cf][0] + bv.x);
          o.y = f2bf(acc[rf][cf][1] + bv.y);
          o.z = f2bf(acc[rf][cf][2] + bv.z);
          o.w = f2bf(acc[rf][cf][3] + bv.w);
          *(ushort4*)(xb + (size_t)row * D + cf * 16 + lg * 4) = o;
        }
      }
    }
  }
}

// ---------------- scans ----------------
__global__ void unisage_scan_k1(const int* __restrict__ in, int* __restrict__ bsum, int n) {
  __shared__ int sh[256];
  int t = threadIdx.x;
  int base = blockIdx.x * 1024 + t * 4;
  int s = 0;
#pragma unroll
  for (int j = 0; j < 4; ++j)
    if (base + j < n) s += in[base + j];
  sh[t] = s;
  __syncthreads();
  for (int o = 128; o > 0; o >>= 1) {
    if (t < o) sh[t] += sh[t + o];
    __syncthreads();
  }
  if (t == 0) bsum[blockIdx.x] = sh[0];
}

// k3 with the block-sum scan folded in: every block locally scans bsum[0..nb)
__global__ void unisage_scan_k3(const int* __restrict__ in, const int* __restrict__ bsum,
                                int* __restrict__ out, int n, int nb) {
  __shared__ int sh[256];
  int t = threadIdx.x;
  int bv = (t < nb) ? bsum[t] : 0;
  sh[t] = bv;
  __syncthreads();
  for (int o = 1; o < 256; o <<= 1) {
    int add = (t >= o) ? sh[t - o] : 0;
    __syncthreads();
    sh[t] += add;
    __syncthreads();
  }
  int bbase = (blockIdx.x == 0) ? 0 : sh[blockIdx.x - 1];
  __syncthreads();

  int base = blockIdx.x * 1024 + t * 4;
  int v[4];
#pragma unroll
  for (int j = 0; j < 4; ++j) v[j] = (base + j < n) ? in[base + j] : 0;
  int tsum = v[0] + v[1] + v[2] + v[3];
  sh[t] = tsum;
  __syncthreads();
  for (int o = 1; o < 256; o <<= 1) {
    int add = (t >= o) ? sh[t - o] : 0;
    __syncthreads();
    sh[t] += add;
    __syncthreads();
  }
  int run = sh[t] - tsum + bbase;
#pragma unroll
  for (int j = 0; j < 4; ++j) {
    if (base + j < n) out[base + j] = run;
    run += v[j];
  }
}

// ---------------- fill_e: edge side only, 2 passes over [0,NE) ----------------
__global__ void unisage_fill_e(const int* __restrict__ nid, const int* __restrict__ eid,
                               const unsigned short* __restrict__ rank_e,
                               const int* __restrict__ off,
                               int* __restrict__ csr_e) {
  const int R = NE / 2;  // 25000
  int pass = blockIdx.x / FILL_B;
  int base = ((blockIdx.x % FILL_B) * 256 + threadIdx.x) * 4;
  if (base >= NZ) return;
  int lo = pass * R, hi = lo + R;
  int4 e4 = *(const int4*)(eid + base);
  int4 n4 = *(const int4*)(nid + base);
  ushort4 re4 = *(const ushort4*)(rank_e + base);
  int e[4] = {e4.x, e4.y, e4.z, e4.w};
  int v[4] = {n4.x, n4.y, n4.z, n4.w};
  unsigned short re[4] = {re4.x, re4.y, re4.z, re4.w};
#pragma unroll
  for (int j = 0; j < 4; ++j) {
    if (e[j] >= lo && e[j] < hi) csr_e[off[e[j]] + (int)re[j]] = v[j];
  }
}

// ---------------- fused: fill_n (blocks [0,G_FILLN)) + edge_agg (rest) ----------------
// edge_agg: 2 EDGES/WAVE (pattern A/B-proven on node_agg, R9/R10: -9us): half-wave
// per edge, 2 rows in flight per half, shfl_xor(16) reduce.
__global__ void unisage_edge_fill(const unsigned short* __restrict__ xb,
                                  const int* __restrict__ csr_e,
                                  const int* __restrict__ off, const int* __restrict__ cnt,
                                  unsigned short* __restrict__ m01b,
                                  const int* __restrict__ nid, const int* __restrict__ eid,
                                  const unsigned short* __restrict__ rank_n,
                                  int* __restrict__ csr_n) {
  if (blockIdx.x < G_FILLN) {
    // ---- fill_n: node side, 2 passes over [NE, NE+NN) ----
    const int R = NN / 2;  // 50000
    int pass = blockIdx.x / FILL_B;
    int base = ((blockIdx.x % FILL_B) * 256 + threadIdx.x) * 4;
    if (base >= NZ) return;
    int lo = NE + pass * R, hi = lo + R;
    int4 e4 = *(const int4*)(eid + base);
    int4 n4 = *(const int4*)(nid + base);
    ushort4 rn4 = *(const ushort4*)(rank_n + base);
    int e[4] = {e4.x, e4.y, e4.z, e4.w};
    int v[4] = {n4.x, n4.y, n4.z, n4.w};
    unsigned short rn[4] = {rn4.x, rn4.y, rn4.z, rn4.w};
#pragma unroll
    for (int j = 0; j < 4; ++j) {
      int s = NE + v[j];
      if (s >= lo && s < hi) csr_n[off[s] + (int)rn[j] - NZ] = e[j];
    }
  } else {
    // ---- edge_agg: 2 edges/wave, 2 rows/instr per half, 16B per lane ----
    int wv = ((blockIdx.x - G_FILLN) * 256 + threadIdx.x) >> 6;  // wave id
    int lane = threadIdx.x & 63;
    int half = lane >> 5;
    int sub = lane & 31;
    int rg = sub >> 4;
    int sl = sub & 15;
    int w = wv * 2 + half;  // edge id
    if (w >= NE) return;
    int beg = off[w];
    int deg = cnt[w];
    int end = beg + deg;
    float a0 = 0, a1 = 0, a2 = 0, a3 = 0, a4 = 0, a5 = 0, a6 = 0, a7 = 0;
    for (int base = beg; base < end; base += 32) {
      int m = min(32, end - base);
      int idx = (sub < m) ? csr_e[base + sub] : 0;
      int iters = (m + 1) >> 1;
      for (int jj = 0; jj < iters; ++jj) {
        int p = 2 * jj + rg;
        int r = __shfl(idx, half * 32 + p, 64);
        if (p < m) {
          uint4 vv = *(const uint4*)(xb + (size_t)r * D + sl * 8);
          a0 += bf2f((unsigned short)(vv.x & 0xffffu)); a1 += bf2f((unsigned short)(vv.x >> 16));
          a2 += bf2f((unsigned short)(vv.y & 0xffffu)); a3 += bf2f((unsigned short)(vv.y >> 16));
          a4 += bf2f((unsigned short)(vv.z & 0xffffu)); a5 += bf2f((unsigned short)(vv.z >> 16));
          a6 += bf2f((unsigned short)(vv.w & 0xffffu)); a7 += bf2f((unsigned short)(vv.w >> 16));
        }
      }
    }
    a0 += __shfl_xor(a0, 16, 64); a1 += __shfl_xor(a1, 16, 64);
    a2 += __shfl_xor(a2, 16, 64); a3 += __shfl_xor(a3, 16, 64);
    a4 += __shfl_xor(a4, 16, 64); a5 += __shfl_xor(a5, 16, 64);
    a6 += __shfl_xor(a6, 16, 64); a7 += __shfl_xor(a7, 16, 64);
    if (rg == 0) {
      uint4 o;
      o.x = (unsigned)f2bf(a0) | ((unsigned)f2bf(a1) << 16);
      o.y = (unsigned)f2bf(a2) | ((unsigned)f2bf(a3) << 16);
      o.z = (unsigned)f2bf(a4) | ((unsigned)f2bf(a5) << 16);
      o.w = (unsigned)f2bf(a6) | ((unsigned)f2bf(a7) << 16);
      *(uint4*)(m01b + (size_t)w * D + sl * 8) = o;
    }
  }
}

// ---------------- node agg: 2 nodes/wave + NT out stores (R9 form, A/B-proven) --------
__global__ void unisage_node_agg(const unsigned short* __restrict__ xb,
                                 const unsigned short* __restrict__ m01b,
                                 const int* __restrict__ csr_n,
                                 const int* __restrict__ off, const int* __restrict__ cnt,
                                 float* __restrict__ out) {
  int wv = (blockIdx.x * 256 + threadIdx.x) >> 6;  // wave id
  int lane = threadIdx.x & 63;
  int half = lane >> 5;
  int sub = lane & 31;
  int rg = sub >> 4;
  int sl = sub & 15;
  int w = wv * 2 + half;  // node id
  if (w >= NN) return;
  int deg = cnt[NE + w];
  int beg = off[NE + w] - NZ;
  int end = beg + deg;
  float a0 = 0, a1 = 0, a2 = 0, a3 = 0, a4 = 0, a5 = 0, a6 = 0, a7 = 0;
  for (int base = beg; base < end; base += 32) {
    int m = min(32, end - base);
    int idx = (sub < m) ? csr_n[base + sub] : 0;
    int iters = (m + 1) >> 1;
    for (int jj = 0; jj < iters; ++jj) {
      int p = 2 * jj + rg;
      int r = __shfl(idx, half * 32 + p, 64);
      if (p < m) {
        uint4 vv = *(const uint4*)(m01b + (size_t)r * D + sl * 8);
        a0 += bf2f((unsigned short)(vv.x & 0xffffu)); a1 += bf2f((unsigned short)(vv.x >> 16));
        a2 += bf2f((unsigned short)(vv.y & 0xffffu)); a3 += bf2f((unsigned short)(vv.y >> 16));
        a4 += bf2f((unsigned short)(vv.z & 0xffffu)); a5 += bf2f((unsigned short)(vv.z >> 16));
        a6 += bf2f((unsigned short)(vv.w & 0xffffu)); a7 += bf2f((unsigned short)(vv.w >> 16));
      }
    }
  }
  a0 += __shfl_xor(a0, 16, 64); a1 += __shfl_xor(a1, 16, 64);
  a2 += __shfl_xor(a2, 16, 64); a3 += __shfl_xor(a3, 16, 64);
  a4 += __shfl_xor(a4, 16, 64); a5 += __shfl_xor(a5, 16, 64);
  a6 += __shfl_xor(a6, 16, 64); a7 += __shfl_xor(a7, 16, 64);
  if (rg == 0) {
    float inv = 1.0f / fmaxf((float)deg, 1.0f);
    uint4 xr = *(const uint4*)(xb + (size_t)w * D + sl * 8);
    f32x4 o0, o1;
    o0[0] = bf2f((unsigned short)(xr.x & 0xffffu)) + a0 * inv;
    o0[1] = bf2f((unsigned short)(xr.x >> 16))     + a1 * inv;
    o0[2] = bf2f((unsigned short)(xr.y & 0xffffu)) + a2 * inv;
    o0[3] = bf2f((unsigned short)(xr.y >> 16))     + a3 * inv;
    o1[0] = bf2f((unsigned short)(xr.z & 0xffffu)) + a4 * inv;
    o1[1] = bf2f((unsigned short)(xr.z >> 16))     + a5 * inv;
    o1[2] = bf2f((unsigned short)(xr.w & 0xffffu)) + a6 * inv;
    o1[3] = bf2f((unsigned short)(xr.w >> 16))     + a7 * inv;
    __builtin_nontemporal_store(o0, (f32x4*)(out + (size_t)w * D + sl * 8));
    __builtin_nontemporal_store(o1, (f32x4*)(out + (size_t)w * D + sl * 8 + 4));
  }
}

extern "C" void kernel_launch(void* const* d_in, const int* in_sizes, int n_in,
                              void* d_out, int out_size, void* d_ws, size_t ws_size,
                              hipStream_t stream) {
  const float* x0   = (const float*)d_in[0];
  const float* W    = (const float*)d_in[1];
  const float* bias = (const float*)d_in[2];
  const int* nid    = (const int*)d_in[3];
  const int* eid    = (const int*)d_in[4];
  float* out = (float*)d_out;

  unsigned short* xb   = (unsigned short*)d_ws;           // NN*D bf16 (25.6 MB)
  unsigned short* m01b = xb + (size_t)NN * D;             // NE*D bf16 (12.8 MB)
  int* cnt   = (int*)(m01b + (size_t)NE * D);             // NSEG
  int* off   = cnt + 150016;                              // NSEG
  unsigned short* rank_e = (unsigned short*)(off + 150016);  // NZ u16
  unsigned short* rank_n = rank_e + NZ;                      // NZ u16
  int* csr_e = (int*)(rank_n + NZ);                       // NZ
  int* csr_n = csr_e + NZ;                                // NZ
  int* bsum  = csr_n + NZ;                                // 256

  hipMemsetAsync(cnt, 0, NSEG * sizeof(int), stream);

  unisage_gemm_hist<<<G_HIST + G_GEMM, 256, 0, stream>>>(x0, W, bias, xb, nid, eid,
                                                         cnt, rank_e, rank_n);

  const int nb = (NSEG + 1023) / 1024;  // 147
  unisage_scan_k1<<<nb, 256, 0, stream>>>(cnt, bsum, NSEG);
  unisage_scan_k3<<<nb, 256, 0, stream>>>(cnt, bsum, off, NSEG, nb);

  unisage_fill_e<<<2 * FILL_B, 256, 0, stream>>>(nid, eid, rank_e, off, csr_e);

  unisage_edge_fill<<<G_FILLN + G_EDGE, 256, 0, stream>>>(xb, csr_e, off, cnt, m01b,
                                                          nid, eid, rank_n, csr_n);

  unisage_node_agg<<<(NN / 2 * 64) / 256, 256, 0, stream>>>(xb, m01b, csr_n, off, cnt, out);
}